// Round 2
// baseline (265.342 us; speedup 1.0000x reference)
//
#include <hip/hip_runtime.h>
#include <math.h>

// (N, Cin, Cout, S, H, W) = (4, 256, 256, 512, 64, 64)
#define NB 4
#define CC 256
#define SS 512
#define NL 6
#define SLOT_HW 65536   // 128 KB per weight slot, MFMA-A-fragment-packed
// ws layout (halfwords): slots 0..6 (conv + 6x mod_w) = [0, 458752)
//   g table (float[6144])  bytes [917504, 942080)
//   barrier counter        byte  942080
#define G_OFF_HW   (7*SLOT_HW)
#define CTR_BYTE   942080

typedef __attribute__((ext_vector_type(8))) short s16x8;
typedef __attribute__((ext_vector_type(4))) float f32x4;
typedef __attribute__((ext_vector_type(2))) float f32x2;
typedef __attribute__((ext_vector_type(4))) unsigned short u16x4;

__device__ __forceinline__ unsigned short f2bf(float f) {
    unsigned u = __builtin_bit_cast(unsigned, f);
    u += 0x7FFFu + ((u >> 16) & 1u);
    return (unsigned short)(u >> 16);
}
// gelu_exact(x) ~= x*sigmoid(1.5957691216*(x+0.044715x^3)), |err|<3e-3
__device__ __forceinline__ float gelu_fast(float x) {
    float u = x * (1.0f + 0.044715f * x * x);
    float e = __expf(-1.5957691216f * u);
    return x * __builtin_amdgcn_rcpf(1.0f + e);
}

// Fragment-packed weight layout, per 256x256 GEMM slot (128 KB):
// fragment f = (m>>4)*8 + (k>>5); inside: halfword offset
//   ((k>>3)&3)*128 + (m&15)*8 + (k&7)
// wave A-fragment read = slot + f*512 + lane*8 (16 B/lane contiguous).

#define BFRAGL(buf, kq, nt, kcl) \
    (lds + (buf)*16384 + ((((kq)*2 + (nt))*2 + (kcl)))*1024)

// ---------------------------------------------------------------------------
// Single PLAIN-launch kernel with a software grid barrier (atomic ctr + spin).
// Residency: 512 blocks, launch_bounds(512,4) -> <=128 VGPR -> 2 blocks/CU
// on 256 CUs = exactly 512 co-resident slots; LDS 69632*2 <= 160K. All blocks
// are guaranteed resident, so the spin cannot deadlock.
//
// g-factorization: wmod rows are uniformly scaled mod_w rows, so
//   h = normalize(mod_w*(s+1)) @ y1  ==  g[m] * (mod_w @ y1),
//   g = t*rsqrt(t^2*Q + eps), t = s+1, Q[l,m] = sum_k mod_w[l][m,k]^2.
// => MFMA A-slots are batch-independent (7 slots total), g applied to acc.
__global__ __launch_bounds__(512, 4) void mono_kernel(
    const float* __restrict__ x, const float* __restrict__ y,
    const float* __restrict__ cw, const float* __restrict__ cb,
    const float* __restrict__ aw, const float* __restrict__ ab,
    const float* __restrict__ mw, unsigned short* __restrict__ wsBF,
    unsigned int* __restrict__ ctr, float* __restrict__ out)
{
    // LDS 69632 B: layer-B dbuf [0,32K) | conv region @32768: xS f32[256][36]
    // (36864 B) during conv staging, then S2 f32[128][33] in the epilogue.
    __shared__ __align__(16) unsigned char lds[69632];
    float* xS = (float*)(lds + 32768);
    float* S2 = (float*)(lds + 32768);
    float* gtab = (float*)(wsBF + G_OFF_HW);

    const int tid  = threadIdx.x;
    const int lane = tid & 63;
    const int w    = tid >> 6;     // wave 0..7: owns m-rows [32w, 32w+32)
    const int l15  = lane & 15;
    const int q    = lane >> 4;    // 0..3

    // XCD swizzle: blockIdx%8 -> (batch, half) per XCD
    const int bswz  = blockIdx.x & 7;
    const int b     = bswz >> 1;               // 0..3
    const int half  = bswz & 1;                // 0..1
    const int strip = blockIdx.x >> 3;         // 0..63
    const int n0    = strip * 64 + half * 32;  // 32-px window

    float y1[2][2][4], y2[2][2][4];
    f32x4 acc[2][2];

    // ---------------- phase P: x staging issue + prep (overlapped) ----------
    float4 xr[4];
#pragma unroll
    for (int p = 0; p < 4; ++p) {      // issue HBM loads first (latency)
        int row = (tid >> 3) + 64*p, c4 = (tid & 7) * 4;
        xr[p] = *(const float4*)&x[((size_t)(b*CC + row))*4096 + n0 + c4];
    }
    // slot packing: 7 slots x 256 rows = 1792 rows; blocks 0..223, 1 row/wave
    if (blockIdx.x < 224) {
        int row = blockIdx.x*8 + w;            // 0..1791
        int sl  = row >> 8, m = row & 255;     // slot 0=conv, 1..6=mod_w[l]
        const float* src = (sl == 0) ? (cw + (size_t)m*CC)
                                     : (mw + ((size_t)(sl-1)*CC + m)*CC);
        unsigned short* dst = wsBF + (size_t)sl*SLOT_HW;
#pragma unroll
        for (int u = 0; u < 4; ++u) {
            int k = lane + 64*u;
            int f = (m >> 4)*8 + (k >> 5);
            int hw = f*512 + ((k >> 3) & 3)*128 + (m & 15)*8 + (k & 7);
            dst[hw] = f2bf(src[k]);
        }
    }
    // g rows: 6144 total = 512 blocks * 12; row work: s-dot(512) + Q-dot(256)
    for (int rr = w; rr < 12; rr += 8) {
        int r  = blockIdx.x*12 + rr;           // 0..6143
        int pl = r >> 10, pb = (r >> 8) & 3, po = r & 255;
        const float* awr = aw + (size_t)(pl*CC + po)*SS;
        const float* yb  = y + (size_t)pb*SS;
        float s = 0.f;
#pragma unroll
        for (int j = 0; j < 8; ++j) { int idx = lane + 64*j; s += awr[idx]*yb[idx]; }
        const float* mwr = mw + ((size_t)pl*CC + po)*CC;
        float qs = 0.f;
#pragma unroll
        for (int u = 0; u < 4; ++u) { float v = mwr[lane + 64*u]; qs += v*v; }
#pragma unroll
        for (int off = 32; off; off >>= 1) {
            s  += __shfl_xor(s, off);
            qs += __shfl_xor(qs, off);
        }
        float t = s + ab[pl*CC + po] + 1.0f;
        if (lane == 0) gtab[r] = t * (1.0f / sqrtf(t*t*qs + 1e-8f));
    }
    // land x into LDS, then build conv-B frags (all local work, pre-barrier)
#pragma unroll
    for (int p = 0; p < 4; ++p) {
        int row = (tid >> 3) + 64*p, c4 = (tid & 7) * 4;
        *(float4*)&xS[row*36 + c4] = xr[p];
    }
    __syncthreads();
    {   // transpose-read (conflict-free) -> bf16 -> ALL conv-B frags (buf0)
        int n = tid & 31, k0 = (tid >> 5) * 16;
        int nt = n >> 4, n15 = n & 15;
#pragma unroll
        for (int j = 0; j < 4; ++j) {
            int k = k0 + 4*j;
            u16x4 hv;
#pragma unroll
            for (int i = 0; i < 4; ++i) hv[i] = f2bf(xS[(k+i)*36 + n]);
            int kq = k >> 6, kcl = (k >> 5) & 1, qq = (k >> 3) & 3, jb = k & 7;
            *(u16x4*)(BFRAGL(0,kq,nt,kcl) + (16*qq + n15)*16 + jb*2) = hv;
        }
    }
    // ---------------- software grid barrier (device-scope) ------------------
    __threadfence();               // release: drain + L2 writeback
    __syncthreads();               // all threads' fences done before arrive
    if (tid == 0) {
        __hip_atomic_fetch_add(ctr, 1u, __ATOMIC_ACQ_REL, __HIP_MEMORY_SCOPE_AGENT);
        while (__hip_atomic_load(ctr, __ATOMIC_ACQUIRE, __HIP_MEMORY_SCOPE_AGENT) < 512u)
            __builtin_amdgcn_s_sleep(2);
    }
    __syncthreads();
    __threadfence();               // acquire: invalidate stale cache lines

    // ---------------- conv GEMM:  acc = cw @ x[b], single-shot --------------
#pragma unroll
    for (int t = 0; t < 2; ++t)
#pragma unroll
        for (int s = 0; s < 2; ++s) acc[t][s] = 0;

    {   // A prefetch (slot 0) depth 4, then one 8-step MFMA phase
        const unsigned short* slot = wsBF;
        s16x8 aS[8][2];
#pragma unroll
        for (int p = 0; p < 4; ++p)
#pragma unroll
        for (int t = 0; t < 2; ++t)
            aS[p][t] = *(const s16x8*)(slot + (size_t)(((2*w+t)*8 + p)*512) + lane*8);
#pragma unroll
        for (int step = 0; step < 8; ++step) {
            if (step < 4) {
#pragma unroll
                for (int t = 0; t < 2; ++t)
                    aS[step+4][t] = *(const s16x8*)(slot + (size_t)(((2*w+t)*8 + step+4)*512) + lane*8);
            }
            int kq = step >> 1, kcl = step & 1;
#pragma unroll
            for (int s = 0; s < 2; ++s) {
                s16x8 bh = *(const s16x8*)(BFRAGL(0,kq,s,kcl) + lane*16);
#pragma unroll
                for (int t = 0; t < 2; ++t)
                    acc[t][s] = __builtin_amdgcn_mfma_f32_16x16x32_bf16(aS[step][t], bh, acc[t][s], 0, 0, 0);
            }
        }
    }

    // conv epilogue: bias + channel-duplication remap via S2 (xS region, dead)
#pragma unroll
    for (int pass = 0; pass < 2; ++pass) {
        __syncthreads();
        if ((w >> 2) == pass) {            // waves owning m in [128pass, +128)
#pragma unroll
            for (int t = 0; t < 2; ++t)
#pragma unroll
            for (int s = 0; s < 2; ++s)
#pragma unroll
            for (int r = 0; r < 4; ++r) {
                int m  = 32*w + 16*t + 4*q + r;
                int nl = 16*s + l15;
                S2[(m - 128*pass)*33 + nl] = acc[t][s][r] + cb[m];
            }
        }
        __syncthreads();
#pragma unroll
        for (int t = 0; t < 2; ++t)
#pragma unroll
        for (int s = 0; s < 2; ++s)
#pragma unroll
        for (int r = 0; r < 4; ++r) {
            int c  = 32*w + 16*t + 4*q + r;
            int nl = 16*s + l15;
            float v = S2[(c >> 1)*33 + nl];
            if (pass == 0) { y1[t][s][r] = v; }
            else           { y2[t][s][r] = v; y1[t][s][r] += v; }
        }
    }
    // y1 = x1+x2, y2 = x2.

    // ---------------- 6 layers: ONE barrier per layer (B dbuf) --------------
    for (int l = 0; l < NL; ++l) {
        const int buf = l & 1;
        const unsigned short* slot = wsBF + (size_t)(1 + l)*SLOT_HW; // batch-indep
#pragma unroll
        for (int t = 0; t < 2; ++t)
#pragma unroll
            for (int s = 0; s < 2; ++s) acc[t][s] = 0;

        // stage B (bf16) from y1 regs: wave w's rows = k-slice [32w,32w+32)
        {
            int kq = w >> 1, kcl = w & 1, jb = 4*(q & 1);
#pragma unroll
            for (int t = 0; t < 2; ++t) {
                int qq = 2*t + (q >> 1);
#pragma unroll
                for (int s = 0; s < 2; ++s) {
                    u16x4 hv;
#pragma unroll
                    for (int r = 0; r < 4; ++r) hv[r] = f2bf(y1[t][s][r]);
                    *(u16x4*)(BFRAGL(buf,kq,s,kcl) + (16*qq + l15)*16 + jb*2) = hv;
                }
            }
        }
        // A prefetch pipeline, depth 4 + g-row scale factors (L2-hot)
        s16x8 aS[8][2];
#pragma unroll
        for (int p = 0; p < 4; ++p)
#pragma unroll
        for (int t = 0; t < 2; ++t)
            aS[p][t] = *(const s16x8*)(slot + (size_t)(((2*w+t)*8 + p)*512) + lane*8);
        float gv[2][4];
#pragma unroll
        for (int t = 0; t < 2; ++t)
#pragma unroll
        for (int r = 0; r < 4; ++r)
            gv[t][r] = gtab[l*1024 + b*256 + 32*w + 16*t + 4*q + r];
        __syncthreads();
        // ONE long MFMA phase: 8 steps, A prefetched 4 steps ahead
#pragma unroll
        for (int step = 0; step < 8; ++step) {
            if (step < 4) {
#pragma unroll
                for (int t = 0; t < 2; ++t)
                    aS[step+4][t] = *(const s16x8*)(slot + (size_t)(((2*w+t)*8 + step+4)*512) + lane*8);
            }
            int kq = step >> 1, kcl = step & 1;
#pragma unroll
            for (int s = 0; s < 2; ++s) {
                s16x8 bh = *(const s16x8*)(BFRAGL(buf,kq,s,kcl) + lane*16);
#pragma unroll
                for (int t = 0; t < 2; ++t)
                    acc[t][s] = __builtin_amdgcn_mfma_f32_16x16x32_bf16(aS[step][t], bh, acc[t][s], 0, 0, 0);
            }
        }
        // h = g*acc; y2 += gelu(h); y1 += y2 (next layer), skip on last.
#pragma unroll
        for (int t = 0; t < 2; ++t)
#pragma unroll
        for (int s = 0; s < 2; ++s)
#pragma unroll
        for (int r = 0; r < 4; ++r) {
            y2[t][s][r] += gelu_fast(acc[t][s][r] * gv[t][r]);
            if (l < NL - 1) y1[t][s][r] += y2[t][s][r];
        }
    }

    // ---------------- out = 0.5*(y1+y2), 2x2 upsample (nontemporal) ---------
#pragma unroll
    for (int t = 0; t < 2; ++t)
#pragma unroll
    for (int s = 0; s < 2; ++s)
#pragma unroll
    for (int r = 0; r < 4; ++r) {
        int ch  = 32*w + 16*t + 4*q + r;
        int wpx = half*32 + 16*s + l15;       // 0..63 source col
        float v = 0.5f*(y1[t][s][r] + y2[t][s][r]);
        f32x2 vv = {v, v};
        size_t base = (((size_t)(b*CC + ch)*128 + 2*strip))*128 + 2*wpx;
        __builtin_nontemporal_store(vv, (f32x2*)&out[base]);
        __builtin_nontemporal_store(vv, (f32x2*)&out[base + 128]);
    }
}

extern "C" void kernel_launch(void* const* d_in, const int* in_sizes, int n_in,
                              void* d_out, int out_size, void* d_ws, size_t ws_size,
                              hipStream_t stream) {
    const float* x  = (const float*)d_in[0];
    const float* y  = (const float*)d_in[1];
    const float* cw = (const float*)d_in[2];
    const float* cb = (const float*)d_in[3];
    const float* aw = (const float*)d_in[4];
    const float* ab = (const float*)d_in[5];
    const float* mw = (const float*)d_in[6];
    float* out = (float*)d_out;

    unsigned short* wsBF = (unsigned short*)d_ws;
    unsigned int* ctr = (unsigned int*)((char*)d_ws + CTR_BYTE);

    // zero the barrier counter (graph-capturable, ordered before the kernel)
    hipMemsetAsync(ctr, 0, 64, stream);
    mono_kernel<<<512, 512, 0, stream>>>(x, y, cw, cb, aw, ab, mw, wsBF, ctr, out);
}

// Round 3
// 121.519 us; speedup vs baseline: 2.1835x; 2.1835x over previous
//
#include <hip/hip_runtime.h>
#include <math.h>

// (N, Cin, Cout, S, H, W) = (4, 256, 256, 512, 64, 64)
#define NB 4
#define CC 256
#define SS 512
#define NL 6
#define SLOT_HW 65536   // 128 KB per weight slot, MFMA-A-fragment-packed
// ws layout (halfwords): slots 0..6 (conv + 6x mod_w[l]) = [0, 458752)
//   g table float[6144] at halfword offset 458752 (byte 917504)
#define G_OFF_HW   (7*SLOT_HW)

typedef __attribute__((ext_vector_type(8))) short s16x8;
typedef __attribute__((ext_vector_type(4))) float f32x4;
typedef __attribute__((ext_vector_type(2))) float f32x2;
typedef __attribute__((ext_vector_type(4))) unsigned short u16x4;

__device__ __forceinline__ unsigned short f2bf(float f) {
    unsigned u = __builtin_bit_cast(unsigned, f);
    u += 0x7FFFu + ((u >> 16) & 1u);
    return (unsigned short)(u >> 16);
}
// gelu_exact(x) ~= x*sigmoid(1.5957691216*(x+0.044715x^3)), |err|<3e-3
__device__ __forceinline__ float gelu_fast(float x) {
    float u = x * (1.0f + 0.044715f * x * x);
    float e = __expf(-1.5957691216f * u);
    return x * __builtin_amdgcn_rcpf(1.0f + e);
}

// Fragment-packed weight layout, per 256x256 GEMM slot (128 KB):
// fragment f = (m>>4)*8 + (k>>5); inside: halfword offset
//   ((k>>3)&3)*128 + (m&15)*8 + (k&7)
// wave A-fragment read = slot + f*512 + lane*8 (16 B/lane contiguous).

// ---------------------------------------------------------------------------
// Prep: g-factorization.  wmod rows are uniformly scaled mod_w rows:
//   h = normalize(mod_w*(s+1)) @ y1  ==  g[l,b,m] * (mod_w[l] @ y1),
//   g = t*rsqrt(t^2*Q + eps), t = s[b,m]+1, Q[l,m] = sum_k mod_w[l][m,k]^2.
// => only 7 batch-independent A-slots (conv + 6 mod_w) + 6144-float g table.
// Blocks [0,448): pack 1792 slot rows (1 row/wave). Blocks [448,832): 1536
// (l,m) rows; each computes s-dots for ALL 4 batches from one aw read + Q.
__global__ __launch_bounds__(256) void prep_kernel(
    const float* __restrict__ y, const float* __restrict__ aw,
    const float* __restrict__ ab, const float* __restrict__ mw,
    const float* __restrict__ cw, unsigned short* __restrict__ wsBF)
{
    int w = threadIdx.x >> 6, lane = threadIdx.x & 63;
    float* gtab = (float*)(wsBF + G_OFF_HW);

    if (blockIdx.x < 448) {            // slot packing: row = slot*256 + m
        int row = blockIdx.x*4 + w;    // 0..1791
        int sl  = row >> 8, m = row & 255;
        const float* src = (sl == 0) ? (cw + (size_t)m*CC)
                                     : (mw + ((size_t)(sl-1)*CC + m)*CC);
        unsigned short* dst = wsBF + (size_t)sl*SLOT_HW;
#pragma unroll
        for (int u = 0; u < 4; ++u) {
            int k = lane + 64*u;
            int f = (m >> 4)*8 + (k >> 5);
            int hw = f*512 + ((k >> 3) & 3)*128 + (m & 15)*8 + (k & 7);
            dst[hw] = f2bf(src[k]);
        }
        return;
    }

    int r  = (blockIdx.x - 448)*4 + w; // 0..1535 = (layer, out-channel)
    int pl = r >> 8, po = r & 255;

    const float* awr = aw + (size_t)(pl*CC + po)*SS;
    float s[4] = {0.f, 0.f, 0.f, 0.f};
#pragma unroll
    for (int j = 0; j < 8; ++j) {
        int idx = lane + 64*j;
        float a = awr[idx];
#pragma unroll
        for (int b = 0; b < 4; ++b) s[b] += a * y[(size_t)b*SS + idx];
    }
    const float* mwr = mw + ((size_t)pl*CC + po)*CC;
    float qs = 0.f;
#pragma unroll
    for (int u = 0; u < 4; ++u) { float v = mwr[lane + 64*u]; qs += v*v; }
#pragma unroll
    for (int off = 32; off; off >>= 1) {
#pragma unroll
        for (int b = 0; b < 4; ++b) s[b] += __shfl_xor(s[b], off);
        qs += __shfl_xor(qs, off);
    }
    float abv = ab[pl*CC + po];
    if (lane < 4) {
        float t = s[lane] + abv + 1.0f;
        gtab[pl*1024 + lane*256 + po] = t * (1.0f / sqrtf(t*t*qs + 1e-8f));
    }
}

// ---------------------------------------------------------------------------
// Fused: one block = (batch, 32-px half-strip, all 256 channels). Grid 512,
// 68 KB LDS -> 2 blocks/CU. Wave w owns m=[32w,32w+32), all n=32. Layer-B
// dbuf -> 1 barrier/layer; A L2->reg prefetch depth 4; g applied on acc.
#define BFRAGL(buf, kq, nt, kcl) \
    (lds + (buf)*16384 + ((((kq)*2 + (nt))*2 + (kcl)))*1024)

__global__ __launch_bounds__(512, 4) void fused_kernel(
    const float* __restrict__ x, const float* __restrict__ cb,
    const unsigned short* __restrict__ wsBF, float* __restrict__ out)
{
    // LDS 69632 B: layer-B dbuf [0,32K) | conv region @32768: xS f32[256][36]
    // (36864 B) during conv staging, then S2 f32[128][33] in the epilogue.
    __shared__ __align__(16) unsigned char lds[69632];
    float* xS = (float*)(lds + 32768);
    float* S2 = (float*)(lds + 32768);
    const float* gtab = (const float*)(wsBF + G_OFF_HW);

    const int tid  = threadIdx.x;
    const int lane = tid & 63;
    const int w    = tid >> 6;     // wave 0..7: owns m-rows [32w, 32w+32)
    const int l15  = lane & 15;
    const int q    = lane >> 4;    // 0..3

    // XCD swizzle: blockIdx%8 -> (batch, half) per XCD; weights L2-resident
    const int bswz  = blockIdx.x & 7;
    const int b     = bswz >> 1;               // 0..3
    const int half  = bswz & 1;                // 0..1
    const int strip = blockIdx.x >> 3;         // 0..63
    const int n0    = strip * 64 + half * 32;  // 32-px window

    float y1[2][2][4], y2[2][2][4];
    f32x4 acc[2][2];

    // ---------------- conv GEMM:  acc = cw @ x[b], single-shot ----------------
#pragma unroll
    for (int t = 0; t < 2; ++t)
#pragma unroll
        for (int s = 0; s < 2; ++s) acc[t][s] = 0;

    {   // stage FULL x window [256k x 32n] fp32, coalesced
#pragma unroll
        for (int p = 0; p < 4; ++p) {
            int row = (tid >> 3) + 64*p, c4 = (tid & 7) * 4;
            float4 v = *(const float4*)&x[((size_t)(b*CC + row))*4096 + n0 + c4];
            *(float4*)&xS[row*36 + c4] = v;
        }
    }
    __syncthreads();
    {   // transpose-read (conflict-free) -> bf16 -> ALL conv-B frags (buf0)
        int n = tid & 31, k0 = (tid >> 5) * 16;
        int nt = n >> 4, n15 = n & 15;
#pragma unroll
        for (int j = 0; j < 4; ++j) {
            int k = k0 + 4*j;
            u16x4 hv;
#pragma unroll
            for (int i = 0; i < 4; ++i) hv[i] = f2bf(xS[(k+i)*36 + n]);
            int kq = k >> 6, kcl = (k >> 5) & 1, qq = (k >> 3) & 3, jb = k & 7;
            *(u16x4*)(BFRAGL(0,kq,nt,kcl) + (16*qq + n15)*16 + jb*2) = hv;
        }
    }
    {   // A prefetch (slot 0) depth 4, then one 8-step MFMA phase
        const unsigned short* slot = wsBF;
        s16x8 aS[8][2];
#pragma unroll
        for (int p = 0; p < 4; ++p)
#pragma unroll
        for (int t = 0; t < 2; ++t)
            aS[p][t] = *(const s16x8*)(slot + (size_t)(((2*w+t)*8 + p)*512) + lane*8);
        __syncthreads();
#pragma unroll
        for (int step = 0; step < 8; ++step) {
            if (step < 4) {
#pragma unroll
                for (int t = 0; t < 2; ++t)
                    aS[step+4][t] = *(const s16x8*)(slot + (size_t)(((2*w+t)*8 + step+4)*512) + lane*8);
            }
            int kq = step >> 1, kcl = step & 1;
#pragma unroll
            for (int s = 0; s < 2; ++s) {
                s16x8 bh = *(const s16x8*)(BFRAGL(0,kq,s,kcl) + lane*16);
#pragma unroll
                for (int t = 0; t < 2; ++t)
                    acc[t][s] = __builtin_amdgcn_mfma_f32_16x16x32_bf16(aS[step][t], bh, acc[t][s], 0, 0, 0);
            }
        }
    }

    // conv epilogue: bias + channel-duplication remap via S2 (xS region, dead).
    // x1[c] = conv[c>>1]+cb, x2[c] = conv[128+(c>>1)]+cb
#pragma unroll
    for (int pass = 0; pass < 2; ++pass) {
        __syncthreads();
        if ((w >> 2) == pass) {            // waves owning m in [128pass, +128)
#pragma unroll
            for (int t = 0; t < 2; ++t)
#pragma unroll
            for (int s = 0; s < 2; ++s)
#pragma unroll
            for (int r = 0; r < 4; ++r) {
                int m  = 32*w + 16*t + 4*q + r;
                int nl = 16*s + l15;
                S2[(m - 128*pass)*33 + nl] = acc[t][s][r] + cb[m];
            }
        }
        __syncthreads();
#pragma unroll
        for (int t = 0; t < 2; ++t)
#pragma unroll
        for (int s = 0; s < 2; ++s)
#pragma unroll
        for (int r = 0; r < 4; ++r) {
            int c  = 32*w + 16*t + 4*q + r;
            int nl = 16*s + l15;
            float v = S2[(c >> 1)*33 + nl];
            if (pass == 0) { y1[t][s][r] = v; }
            else           { y2[t][s][r] = v; y1[t][s][r] += v; }
        }
    }
    // y1 = x1+x2, y2 = x2.  No barrier needed: layer-0 staging targets buf0
    // [0,16K), disjoint from S2 @32768; buf0's conv reads were fenced by the
    // epilogue's first __syncthreads.

    // ---------------- 6 layers: ONE barrier per layer (B dbuf) ----------------
    for (int l = 0; l < NL; ++l) {
        const int buf = l & 1;
        const unsigned short* slot = wsBF + (size_t)(1 + l)*SLOT_HW; // batch-indep
#pragma unroll
        for (int t = 0; t < 2; ++t)
#pragma unroll
            for (int s = 0; s < 2; ++s) acc[t][s] = 0;

        // stage B (bf16) from y1 regs: wave w's rows = k-slice [32w,32w+32)
        {
            int kq = w >> 1, kcl = w & 1, jb = 4*(q & 1);
#pragma unroll
            for (int t = 0; t < 2; ++t) {
                int qq = 2*t + (q >> 1);
#pragma unroll
                for (int s = 0; s < 2; ++s) {
                    u16x4 hv;
#pragma unroll
                    for (int r = 0; r < 4; ++r) hv[r] = f2bf(y1[t][s][r]);
                    *(u16x4*)(BFRAGL(buf,kq,s,kcl) + (16*qq + l15)*16 + jb*2) = hv;
                }
            }
        }
        // A prefetch pipeline, depth 4 + g-row scale factors (L2-hot)
        s16x8 aS[8][2];
#pragma unroll
        for (int p = 0; p < 4; ++p)
#pragma unroll
        for (int t = 0; t < 2; ++t)
            aS[p][t] = *(const s16x8*)(slot + (size_t)(((2*w+t)*8 + p)*512) + lane*8);
        float gv[2][4];
#pragma unroll
        for (int t = 0; t < 2; ++t)
#pragma unroll
        for (int r = 0; r < 4; ++r)
            gv[t][r] = gtab[l*1024 + b*256 + 32*w + 16*t + 4*q + r];
        __syncthreads();
        // ONE long MFMA phase: 8 steps, A prefetched 4 steps ahead
#pragma unroll
        for (int step = 0; step < 8; ++step) {
            if (step < 4) {
#pragma unroll
                for (int t = 0; t < 2; ++t)
                    aS[step+4][t] = *(const s16x8*)(slot + (size_t)(((2*w+t)*8 + step+4)*512) + lane*8);
            }
            int kq = step >> 1, kcl = step & 1;
#pragma unroll
            for (int s = 0; s < 2; ++s) {
                s16x8 bh = *(const s16x8*)(BFRAGL(buf,kq,s,kcl) + lane*16);
#pragma unroll
                for (int t = 0; t < 2; ++t)
                    acc[t][s] = __builtin_amdgcn_mfma_f32_16x16x32_bf16(aS[step][t], bh, acc[t][s], 0, 0, 0);
            }
        }
        // h = g*acc; y2 += gelu(h); y1 += y2 (next layer), skip on last.
        // No trailing barrier: next layer stages the OTHER buffer.
#pragma unroll
        for (int t = 0; t < 2; ++t)
#pragma unroll
        for (int s = 0; s < 2; ++s)
#pragma unroll
        for (int r = 0; r < 4; ++r) {
            y2[t][s][r] += gelu_fast(acc[t][s][r] * gv[t][r]);
            if (l < NL - 1) y1[t][s][r] += y2[t][s][r];
        }
    }

    // ---------------- out = 0.5*(y1+y2), 2x2 upsample (nontemporal) --------
#pragma unroll
    for (int t = 0; t < 2; ++t)
#pragma unroll
    for (int s = 0; s < 2; ++s)
#pragma unroll
    for (int r = 0; r < 4; ++r) {
        int ch  = 32*w + 16*t + 4*q + r;
        int wpx = half*32 + 16*s + l15;       // 0..63 source col
        float v = 0.5f*(y1[t][s][r] + y2[t][s][r]);
        f32x2 vv = {v, v};
        size_t base = (((size_t)(b*CC + ch)*128 + 2*strip))*128 + 2*wpx;
        __builtin_nontemporal_store(vv, (f32x2*)&out[base]);
        __builtin_nontemporal_store(vv, (f32x2*)&out[base + 128]);
    }
}

extern "C" void kernel_launch(void* const* d_in, const int* in_sizes, int n_in,
                              void* d_out, int out_size, void* d_ws, size_t ws_size,
                              hipStream_t stream) {
    const float* x  = (const float*)d_in[0];
    const float* y  = (const float*)d_in[1];
    const float* cw = (const float*)d_in[2];
    const float* cb = (const float*)d_in[3];
    const float* aw = (const float*)d_in[4];
    const float* ab = (const float*)d_in[5];
    const float* mw = (const float*)d_in[6];
    float* out = (float*)d_out;

    unsigned short* wsBF = (unsigned short*)d_ws;   // 7 slots + g table < 1 MB

    prep_kernel<<<832, 256, 0, stream>>>(y, aw, ab, mw, cw, wsBF);
    fused_kernel<<<512, 512, 0, stream>>>(x, cb, wsBF, out);
}

// Round 4
// 119.699 us; speedup vs baseline: 2.2167x; 1.0152x over previous
//
#include <hip/hip_runtime.h>
#include <math.h>

// (N, Cin, Cout, S, H, W) = (4, 256, 256, 512, 64, 64)
#define NB 4
#define CC 256
#define SS 512
#define NL 6
#define SLOT_HW 65536   // 128 KB per weight slot, MFMA-A-fragment-packed
// ws layout (halfwords): slots 0..6 (conv + 6x mod_w[l]) = [0, 458752)
//   g table float[6144] at halfword offset 458752 (byte 917504)
#define G_OFF_HW   (7*SLOT_HW)

typedef __attribute__((ext_vector_type(8))) short s16x8;
typedef __attribute__((ext_vector_type(4))) float f32x4;
typedef __attribute__((ext_vector_type(2))) float f32x2;
typedef __attribute__((ext_vector_type(4))) unsigned short u16x4;

__device__ __forceinline__ unsigned short f2bf(float f) {
    unsigned u = __builtin_bit_cast(unsigned, f);
    u += 0x7FFFu + ((u >> 16) & 1u);
    return (unsigned short)(u >> 16);
}
// packed RNE f32->bf16 pair: dst[15:0]=cvt(lo), dst[31:16]=cvt(hi)
__device__ __forceinline__ unsigned cvt_pk_bf16(float lo, float hi) {
    unsigned r;
    asm("v_cvt_pk_bf16_f32 %0, %1, %2" : "=v"(r) : "v"(lo), "v"(hi));
    return r;
}
// gelu_exact(x) ~= x*sigmoid(1.5957691216*(x+0.044715x^3)), |err|<3e-3
__device__ __forceinline__ float gelu_fast(float x) {
    float u = x * (1.0f + 0.044715f * x * x);
    float e = __expf(-1.5957691216f * u);
    return x * __builtin_amdgcn_rcpf(1.0f + e);
}

// Fragment-packed weight layout, per 256x256 GEMM slot (128 KB):
// fragment f = (m>>4)*8 + (k>>5); inside: halfword offset
//   ((k>>3)&3)*128 + (m&15)*8 + (k&7)
// wave A-fragment read = slot + f*512 + lane*8 (16 B/lane contiguous).

// ---------------------------------------------------------------------------
// Prep: g-factorization.  wmod rows are uniformly scaled mod_w rows:
//   h = normalize(mod_w*(s+1)) @ y1  ==  g[l,b,m] * (mod_w[l] @ y1),
//   g = t*rsqrt(t^2*Q + eps), t = s[b,m]+1, Q[l,m] = sum_k mod_w[l][m,k]^2.
// => only 7 batch-independent A-slots (conv + 6 mod_w) + 6144-float g table.
__global__ __launch_bounds__(256) void prep_kernel(
    const float* __restrict__ y, const float* __restrict__ aw,
    const float* __restrict__ ab, const float* __restrict__ mw,
    const float* __restrict__ cw, unsigned short* __restrict__ wsBF)
{
    int w = threadIdx.x >> 6, lane = threadIdx.x & 63;
    float* gtab = (float*)(wsBF + G_OFF_HW);

    if (blockIdx.x < 448) {            // slot packing: row = slot*256 + m
        int row = blockIdx.x*4 + w;    // 0..1791
        int sl  = row >> 8, m = row & 255;
        const float* src = (sl == 0) ? (cw + (size_t)m*CC)
                                     : (mw + ((size_t)(sl-1)*CC + m)*CC);
        unsigned short* dst = wsBF + (size_t)sl*SLOT_HW;
#pragma unroll
        for (int u = 0; u < 4; ++u) {
            int k = lane + 64*u;
            int f = (m >> 4)*8 + (k >> 5);
            int hw = f*512 + ((k >> 3) & 3)*128 + (m & 15)*8 + (k & 7);
            dst[hw] = f2bf(src[k]);
        }
        return;
    }

    int r  = (blockIdx.x - 448)*4 + w; // 0..1535 = (layer, out-channel)
    int pl = r >> 8, po = r & 255;

    const float* awr = aw + (size_t)(pl*CC + po)*SS;
    float s[4] = {0.f, 0.f, 0.f, 0.f};
#pragma unroll
    for (int j = 0; j < 8; ++j) {
        int idx = lane + 64*j;
        float a = awr[idx];
#pragma unroll
        for (int b = 0; b < 4; ++b) s[b] += a * y[(size_t)b*SS + idx];
    }
    const float* mwr = mw + ((size_t)pl*CC + po)*CC;
    float qs = 0.f;
#pragma unroll
    for (int u = 0; u < 4; ++u) { float v = mwr[lane + 64*u]; qs += v*v; }
#pragma unroll
    for (int off = 32; off; off >>= 1) {
#pragma unroll
        for (int b = 0; b < 4; ++b) s[b] += __shfl_xor(s[b], off);
        qs += __shfl_xor(qs, off);
    }
    float abv = ab[pl*CC + po];
    if (lane < 4) {
        float t = s[lane] + abv + 1.0f;
        gtab[pl*1024 + lane*256 + po] = t * (1.0f / sqrtf(t*t*qs + 1e-8f));
    }
}

// ---------------------------------------------------------------------------
// Fused: one block = (batch, 32-px half-strip, all 256 channels). Grid 512,
// 68 KB LDS -> 2 blocks/CU. Wave w owns m=[32w,32w+32), all n=32. Layer-B
// dbuf -> 1 barrier/layer; A L2->reg prefetch depth 4; g applied on acc.
#define BFRAGL(buf, kq, nt, kcl) \
    (lds + (buf)*16384 + ((((kq)*2 + (nt))*2 + (kcl)))*1024)

__global__ __launch_bounds__(512, 4) void fused_kernel(
    const float* __restrict__ x, const float* __restrict__ cb,
    const unsigned short* __restrict__ wsBF, float* __restrict__ out)
{
    // LDS 69632 B: layer-B dbuf [0,32K) | conv region @32768: xS f32[256][36]
    // (36864 B) during conv staging, then S2 f32[128][33] in the epilogue.
    __shared__ __align__(16) unsigned char lds[69632];
    float* xS = (float*)(lds + 32768);
    float* S2 = (float*)(lds + 32768);
    const float* gtab = (const float*)(wsBF + G_OFF_HW);

    const int tid  = threadIdx.x;
    const int lane = tid & 63;
    const int w    = tid >> 6;     // wave 0..7: owns m-rows [32w, 32w+32)
    const int l15  = lane & 15;
    const int q    = lane >> 4;    // 0..3

    // XCD swizzle: blockIdx%8 -> (batch, half) per XCD; weights L2-resident
    const int bswz  = blockIdx.x & 7;
    const int b     = bswz >> 1;               // 0..3
    const int half  = bswz & 1;                // 0..1
    const int strip = blockIdx.x >> 3;         // 0..63
    const int n0    = strip * 64 + half * 32;  // 32-px window

    float y1[2][2][4], y2[2][2][4];
    f32x4 acc[2][2];

    // ---------------- conv GEMM:  acc = cw @ x[b], single-shot ----------------
#pragma unroll
    for (int t = 0; t < 2; ++t)
#pragma unroll
        for (int s = 0; s < 2; ++s) acc[t][s] = 0;

    // issue x window loads (HBM) FIRST, then conv A-prefetch (L2/HBM) so the
    // slot-0 latency hides under LDS staging + transpose-build
    float4 xr[4];
#pragma unroll
    for (int p = 0; p < 4; ++p) {
        int row = (tid >> 3) + 64*p, c4 = (tid & 7) * 4;
        xr[p] = *(const float4*)&x[((size_t)(b*CC + row))*4096 + n0 + c4];
    }
    s16x8 aS[8][2];
#pragma unroll
    for (int p = 0; p < 4; ++p)
#pragma unroll
    for (int t = 0; t < 2; ++t)
        aS[p][t] = *(const s16x8*)(wsBF + (size_t)(((2*w+t)*8 + p)*512) + lane*8);

#pragma unroll
    for (int p = 0; p < 4; ++p) {      // land x into LDS
        int row = (tid >> 3) + 64*p, c4 = (tid & 7) * 4;
        *(float4*)&xS[row*36 + c4] = xr[p];
    }
    __syncthreads();
    {   // transpose-read (conflict-free) -> bf16 -> ALL conv-B frags (buf0)
        int n = tid & 31, k0 = (tid >> 5) * 16;
        int nt = n >> 4, n15 = n & 15;
#pragma unroll
        for (int j = 0; j < 4; ++j) {
            int k = k0 + 4*j;
            float v0 = xS[(k+0)*36 + n], v1 = xS[(k+1)*36 + n];
            float v2 = xS[(k+2)*36 + n], v3 = xS[(k+3)*36 + n];
            uint2 hv; hv.x = cvt_pk_bf16(v0, v1); hv.y = cvt_pk_bf16(v2, v3);
            int kq = k >> 6, kcl = (k >> 5) & 1, qq = (k >> 3) & 3, jb = k & 7;
            *(uint2*)(BFRAGL(0,kq,nt,kcl) + (16*qq + n15)*16 + jb*2) = hv;
        }
    }
    __syncthreads();
    {   // one 8-step MFMA phase, A prefetched 4 ahead
        const unsigned short* slot = wsBF;
        __builtin_amdgcn_s_setprio(1);
#pragma unroll
        for (int step = 0; step < 8; ++step) {
            if (step < 4) {
#pragma unroll
                for (int t = 0; t < 2; ++t)
                    aS[step+4][t] = *(const s16x8*)(slot + (size_t)(((2*w+t)*8 + step+4)*512) + lane*8);
            }
            int kq = step >> 1, kcl = step & 1;
#pragma unroll
            for (int s = 0; s < 2; ++s) {
                s16x8 bh = *(const s16x8*)(BFRAGL(0,kq,s,kcl) + lane*16);
#pragma unroll
                for (int t = 0; t < 2; ++t)
                    acc[t][s] = __builtin_amdgcn_mfma_f32_16x16x32_bf16(aS[step][t], bh, acc[t][s], 0, 0, 0);
            }
        }
        __builtin_amdgcn_s_setprio(0);
    }

    // conv epilogue: bias + channel-duplication remap via S2 (xS region, dead).
    // x1[c] = conv[c>>1]+cb, x2[c] = conv[128+(c>>1)]+cb
#pragma unroll
    for (int pass = 0; pass < 2; ++pass) {
        __syncthreads();
        if ((w >> 2) == pass) {            // waves owning m in [128pass, +128)
#pragma unroll
            for (int t = 0; t < 2; ++t)
#pragma unroll
            for (int s = 0; s < 2; ++s)
#pragma unroll
            for (int r = 0; r < 4; ++r) {
                int m  = 32*w + 16*t + 4*q + r;
                int nl = 16*s + l15;
                S2[(m - 128*pass)*33 + nl] = acc[t][s][r] + cb[m];
            }
        }
        __syncthreads();
#pragma unroll
        for (int t = 0; t < 2; ++t)
#pragma unroll
        for (int s = 0; s < 2; ++s)
#pragma unroll
        for (int r = 0; r < 4; ++r) {
            int c  = 32*w + 16*t + 4*q + r;
            int nl = 16*s + l15;
            float v = S2[(c >> 1)*33 + nl];
            if (pass == 0) { y1[t][s][r] = v; }
            else           { y2[t][s][r] = v; y1[t][s][r] += v; }
        }
    }
    // y1 = x1+x2, y2 = x2.  No barrier needed: layer-0 staging targets buf0
    // [0,16K), disjoint from S2 @32768; buf0's conv reads were fenced by the
    // epilogue's first __syncthreads.

    // ---------------- 6 layers: ONE barrier per layer (B dbuf) ----------------
    for (int l = 0; l < NL; ++l) {
        const int buf = l & 1;
        const unsigned short* slot = wsBF + (size_t)(1 + l)*SLOT_HW; // batch-indep
#pragma unroll
        for (int t = 0; t < 2; ++t)
#pragma unroll
            for (int s = 0; s < 2; ++s) acc[t][s] = 0;

        // issue A-prefetch (depth 4) + g loads FIRST (L2 latency hides under
        // the B-stage packing below)
#pragma unroll
        for (int p = 0; p < 4; ++p)
#pragma unroll
        for (int t = 0; t < 2; ++t)
            aS[p][t] = *(const s16x8*)(slot + (size_t)(((2*w+t)*8 + p)*512) + lane*8);
        float4 gv[2];
#pragma unroll
        for (int t = 0; t < 2; ++t)
            gv[t] = *(const float4*)&gtab[l*1024 + b*256 + 32*w + 16*t + 4*q];

        // stage B (bf16) from y1 regs: wave w's rows = k-slice [32w,32w+32)
        {
            int kq = w >> 1, kcl = w & 1, jb = 4*(q & 1);
#pragma unroll
            for (int t = 0; t < 2; ++t) {
                int qq = 2*t + (q >> 1);
#pragma unroll
                for (int s = 0; s < 2; ++s) {
                    uint2 hv;
                    hv.x = cvt_pk_bf16(y1[t][s][0], y1[t][s][1]);
                    hv.y = cvt_pk_bf16(y1[t][s][2], y1[t][s][3]);
                    *(uint2*)(BFRAGL(buf,kq,s,kcl) + (16*qq + l15)*16 + jb*2) = hv;
                }
            }
        }
        __syncthreads();
        // ONE long MFMA phase: 8 steps, A prefetched 4 steps ahead
        __builtin_amdgcn_s_setprio(1);
#pragma unroll
        for (int step = 0; step < 8; ++step) {
            if (step < 4) {
#pragma unroll
                for (int t = 0; t < 2; ++t)
                    aS[step+4][t] = *(const s16x8*)(slot + (size_t)(((2*w+t)*8 + step+4)*512) + lane*8);
            }
            int kq = step >> 1, kcl = step & 1;
#pragma unroll
            for (int s = 0; s < 2; ++s) {
                s16x8 bh = *(const s16x8*)(BFRAGL(buf,kq,s,kcl) + lane*16);
#pragma unroll
                for (int t = 0; t < 2; ++t)
                    acc[t][s] = __builtin_amdgcn_mfma_f32_16x16x32_bf16(aS[step][t], bh, acc[t][s], 0, 0, 0);
            }
        }
        __builtin_amdgcn_s_setprio(0);
        // h = g*acc; y2 += gelu(h); y1 += y2 (next layer), skip on last.
        // No trailing barrier: next layer stages the OTHER buffer.
#pragma unroll
        for (int t = 0; t < 2; ++t)
#pragma unroll
        for (int s = 0; s < 2; ++s)
#pragma unroll
        for (int r = 0; r < 4; ++r) {
            y2[t][s][r] += gelu_fast(acc[t][s][r] * gv[t][r]);
            if (l < NL - 1) y1[t][s][r] += y2[t][s][r];
        }
    }

    // ---------------- out = 0.5*(y1+y2), 2x2 upsample (nontemporal) --------
#pragma unroll
    for (int t = 0; t < 2; ++t)
#pragma unroll
    for (int s = 0; s < 2; ++s)
#pragma unroll
    for (int r = 0; r < 4; ++r) {
        int ch  = 32*w + 16*t + 4*q + r;
        int wpx = half*32 + 16*s + l15;       // 0..63 source col
        float v = 0.5f*(y1[t][s][r] + y2[t][s][r]);
        f32x2 vv = {v, v};
        size_t base = (((size_t)(b*CC + ch)*128 + 2*strip))*128 + 2*wpx;
        __builtin_nontemporal_store(vv, (f32x2*)&out[base]);
        __builtin_nontemporal_store(vv, (f32x2*)&out[base + 128]);
    }
}

extern "C" void kernel_launch(void* const* d_in, const int* in_sizes, int n_in,
                              void* d_out, int out_size, void* d_ws, size_t ws_size,
                              hipStream_t stream) {
    const float* x  = (const float*)d_in[0];
    const float* y  = (const float*)d_in[1];
    const float* cw = (const float*)d_in[2];
    const float* cb = (const float*)d_in[3];
    const float* aw = (const float*)d_in[4];
    const float* ab = (const float*)d_in[5];
    const float* mw = (const float*)d_in[6];
    float* out = (float*)d_out;

    unsigned short* wsBF = (unsigned short*)d_ws;   // 7 slots + g table < 1 MB

    prep_kernel<<<832, 256, 0, stream>>>(y, aw, ab, mw, cw, wsBF);
    fused_kernel<<<512, 512, 0, stream>>>(x, cb, wsBF, out);
}